// Round 1
// baseline (1224.420 us; speedup 1.0000x reference)
//
#include <hip/hip_runtime.h>
#include <hip/hip_bf16.h>
#include <math.h>

// ---------------------------------------------------------------------------
// Diffusion renoise-loop + conditional MLP loss, MI355X (gfx950).
//
// JAX RNG mode: 1 = threefry_partitionable (modern JAX default),
//               0 = original threefry random_bits/split (pre-0.4.36 default).
// If bench fails with absmax ~0.1-0.5, flip this to 0.
#define JAX_PARTITIONABLE 1

#define BS   128
#define NS   1024
#define DIM  6
#define HID  512
#define CTX  128
#define TT   100
#define ITERS 8

// ---- workspace layout (bytes) ---------------------------------------------
constexpr size_t OFF_SACP  = 0;        // 100 f32 (pad 512)
constexpr size_t OFF_S1M   = 512;      // 100 f32 (pad 512)
constexpr size_t OFF_KEYS  = 1024;     // 16 u32
constexpr size_t OFF_CNTG  = 1152;     // 8 u32 global mismatch counts
constexpr size_t OFF_CNTB  = 1280;     // 8*128 u32 per-batch counts -> 5376
constexpr size_t OFF_LIST  = 8192;     // u16 [2][128][1024] = 524288 -> 532480
constexpr size_t OFF_DATAP = 532480;   // float4[131072*2] = 4 MiB -> 4726784
constexpr size_t OFF_NOISE = 4726784;  // f32 [128*1024*3] -> 6299648
constexpr size_t OFF_NOISY = 6299648;  // f32 [128*1024*3] -> 7872512
constexpr size_t OFF_BIAS  = 7872512;  // f32 [128*512]    -> 8134656
constexpr size_t OFF_PA    = 8134656;  // float4[512]
constexpr size_t OFF_PB    = 8142848;  // float4[512]
constexpr size_t OFF_PC    = 8151040;  // f32[512] -> 8153088 total ~8.2 MB

// ---- threefry2x32-20 -------------------------------------------------------
__device__ __forceinline__ unsigned rotl32(unsigned x, int r) {
  return (x << r) | (x >> (32 - r));
}
__device__ __forceinline__ void tf2x32(unsigned k0, unsigned k1,
                                       unsigned x0, unsigned x1,
                                       unsigned& o0, unsigned& o1) {
  unsigned k2 = k0 ^ k1 ^ 0x1BD11BDAu;
  x0 += k0; x1 += k1;
#define TF_R4(a,b,c,d) \
  x0 += x1; x1 = rotl32(x1,(a)); x1 ^= x0; \
  x0 += x1; x1 = rotl32(x1,(b)); x1 ^= x0; \
  x0 += x1; x1 = rotl32(x1,(c)); x1 ^= x0; \
  x0 += x1; x1 = rotl32(x1,(d)); x1 ^= x0;
  TF_R4(13,15,26,6)   x0 += k1; x1 += k2 + 1u;
  TF_R4(17,29,16,24)  x0 += k2; x1 += k0 + 2u;
  TF_R4(13,15,26,6)   x0 += k0; x1 += k1 + 3u;
  TF_R4(17,29,16,24)  x0 += k1; x1 += k2 + 4u;
  TF_R4(13,15,26,6)   x0 += k2; x1 += k0 + 5u;
#undef TF_R4
  o0 = x0; o1 = x1;
}

// bits -> uniform in [nextafter(-1,0), 1) exactly as jax._src.random._uniform
__device__ __forceinline__ float bits_to_u(unsigned bits) {
  float f = __uint_as_float((bits >> 9) | 0x3f800000u) - 1.0f;
  // (maxval - minval) rounds to exactly 2.0f in fp32; mul by 2 is exact.
  float u = f * 2.0f + (-0.99999994f);
  return fmaxf(-0.99999994f, u);
}

__device__ __forceinline__ float nrm_from_idx(unsigned k0, unsigned k1, unsigned idx) {
#if JAX_PARTITIONABLE
  unsigned o0, o1;
  tf2x32(k0, k1, 0u, idx, o0, o1);
  unsigned bits = o0 ^ o1;
#else
  const unsigned H = (BS * NS * DIM) / 2;  // 393216
  unsigned o0, o1, bits;
  if (idx < H) { tf2x32(k0, k1, idx, idx + H, o0, o1); bits = o0; }
  else         { tf2x32(k0, k1, idx - H, idx, o0, o1); bits = o1; }
#endif
  return 1.41421356f * erfinvf(bits_to_u(bits));  // sqrt(2) as fp32 0x3FB504F3
}

// regenerate the 3 free-dim noise values of point p with iteration key (k0,k1)
__device__ __forceinline__ void regen3(unsigned k0, unsigned k1, int p,
                                       float a, float s,
                                       const float* __restrict__ data,
                                       float* __restrict__ noise_f,
                                       float* __restrict__ noisy_f,
                                       float& y3, float& y4, float& y5) {
  unsigned base = (unsigned)p * 6u;
  float z3 = nrm_from_idx(k0, k1, base + 3u);
  float z4 = nrm_from_idx(k0, k1, base + 4u);
  float z5 = nrm_from_idx(k0, k1, base + 5u);
  noise_f[p*3+0] = z3; noise_f[p*3+1] = z4; noise_f[p*3+2] = z5;
  // match XLA: round(a*d) + round(s*z)
  y3 = __fadd_rn(__fmul_rn(a, data[p*6+3]), __fmul_rn(s, z3));
  y4 = __fadd_rn(__fmul_rn(a, data[p*6+4]), __fmul_rn(s, z4));
  y5 = __fadd_rn(__fmul_rn(a, data[p*6+5]), __fmul_rn(s, z5));
  noisy_f[p*3+0] = y3; noisy_f[p*3+1] = y4; noisy_f[p*3+2] = y5;
}

// ---- kernel 1: tables, iteration keys, counter init ------------------------
__global__ void k_init(float* __restrict__ sacp, float* __restrict__ s1m,
                       unsigned* __restrict__ keys, unsigned* __restrict__ cntg,
                       unsigned* __restrict__ cntb) {
  int t = threadIdx.x;
  if (t == 0) {
    const double PI = 3.14159265358979323846;
    double acp = 1.0;
    for (int i = 0; i < TT; ++i) {
      double t0 = (double)i / TT, t1 = (double)(i + 1) / TT;
      double c0 = cos((t0 + 0.008) / 1.008 * PI * 0.5); double ab0 = c0 * c0;
      double c1 = cos((t1 + 0.008) / 1.008 * PI * 0.5); double ab1 = c1 * c1;
      double beta = 1.0 - ab1 / ab0;
      if (beta > 0.999) beta = 0.999;
      acp *= (1.0 - beta);
      sacp[i] = (float)sqrt(acp);
      s1m[i]  = (float)sqrt(1.0 - acp);
    }
  }
  if (t == 1) {
    // keys for the 8 scan iterations, from jax.random.split(key(42), 8)
#if JAX_PARTITIONABLE
    for (int k = 0; k < ITERS; ++k) {
      unsigned o0, o1;
      tf2x32(0u, 42u, 0u, (unsigned)k, o0, o1);
      keys[2*k] = o0; keys[2*k+1] = o1;
    }
#else
    unsigned outw[16];
    for (int i = 0; i < 8; ++i) {
      unsigned o0, o1;
      tf2x32(0u, 42u, (unsigned)i, (unsigned)(i + 8), o0, o1);
      outw[i] = o0; outw[8 + i] = o1;
    }
    for (int k = 0; k < ITERS; ++k) { keys[2*k] = outw[2*k]; keys[2*k+1] = outw[2*k+1]; }
#endif
  }
  for (int i = t; i < ITERS; i += blockDim.x) cntg[i] = 0u;
  for (int i = t; i < ITERS * BS; i += blockDim.x) cntb[i] = 0u;
}

// ---- kernel 2: pack data {d0..d5,|d|^2,0}, init noise/noisy (free dims) ----
__global__ __launch_bounds__(256) void k_prep(
    const float* __restrict__ data, const float* __restrict__ noise0,
    const int* __restrict__ ts, const float* __restrict__ sacp,
    const float* __restrict__ s1m,
    float4* __restrict__ dataP, float* __restrict__ noise_f,
    float* __restrict__ noisy_f) {
  int p = blockIdx.x * 256 + threadIdx.x;  // 0..131071
  int b = p >> 10;
  int t = ts[b];
  float a = sacp[t], s = s1m[t];
  const float* dp = data + (size_t)p * 6;
  float d0 = dp[0], d1 = dp[1], d2 = dp[2], d3 = dp[3], d4 = dp[4], d5 = dp[5];
  float dsq = d0*d0;
  dsq = fmaf(d1, d1, dsq); dsq = fmaf(d2, d2, dsq);
  dsq = fmaf(d3, d3, dsq); dsq = fmaf(d4, d4, dsq); dsq = fmaf(d5, d5, dsq);
  dataP[2*p]   = make_float4(d0, d1, d2, d3);
  dataP[2*p+1] = make_float4(d4, d5, dsq, 0.f);
  const float* np0 = noise0 + (size_t)p * 6;
  for (int f = 0; f < 3; ++f) {
    float z = np0[3 + f];
    noise_f[p*3 + f] = z;
    noisy_f[p*3 + f] = __fadd_rn(__fmul_rn(a, dp[3 + f]), __fmul_rn(s, z));
  }
}

// ---- kernel 3: per-(b,j) bias = c@Wc + (t/T)*Wt + b1 -----------------------
__global__ __launch_bounds__(256) void k_bias(
    const float* __restrict__ ctx, const float* __restrict__ Wc,
    const float* __restrict__ Wt, const float* __restrict__ b1,
    const int* __restrict__ ts, float* __restrict__ biasb) {
  int idx = blockIdx.x * 256 + threadIdx.x;  // 0..65535
  int b = idx >> 9, j = idx & 511;
  const float* c = ctx + (size_t)b * CTX;
  float acc = 0.f;
  for (int q = 0; q < CTX; ++q) acc = fmaf(c[q], Wc[q * HID + j], acc);
  float temb = (float)ts[b] / 100.0f;
  biasb[idx] = acc + temb * Wt[j] + b1[j];
}

// ---- kernel 4: pack MLP weights for broadcast loads ------------------------
__global__ void k_pack(const float* __restrict__ W1, const float* __restrict__ W2,
                       float4* __restrict__ PA, float4* __restrict__ PB,
                       float* __restrict__ PC) {
  int j = blockIdx.x * 256 + threadIdx.x;
  if (j >= HID) return;
  PA[j] = make_float4(W1[j], W1[512 + j], W1[1024 + j], W1[1536 + j]);
  PB[j] = make_float4(W1[2048 + j], W1[2560 + j], W2[j*6 + 3], W2[j*6 + 4]);
  PC[j] = W2[j*6 + 5];
}

// ---- kernel 5: fused [apply update k-1] + [argmin k] + compact survivors ---
__global__ __launch_bounds__(256) void k_argmin(
    int k,
    const float* __restrict__ data, const int* __restrict__ ts,
    const float* __restrict__ sacp, const float* __restrict__ s1m,
    const unsigned* __restrict__ keys, unsigned* __restrict__ cntg,
    unsigned* __restrict__ cntb, unsigned short* __restrict__ list,
    const float4* __restrict__ dataP, float* __restrict__ noise_f,
    float* __restrict__ noisy_f) {
  int b = blockIdx.x >> 2, chunk = blockIdx.x & 3;
  if (k > 0) {
    // cont_{k-1} requires every previous global mismatch count >= 10
    for (int j = 0; j < k; ++j) if (cntg[j] < 10u) return;
  }
  int cb = (k == 0) ? NS : (int)cntb[(k - 1) * BS + b];
  if (chunk * 256 >= cb) return;  // block-uniform
  int i = chunk * 256 + (int)threadIdx.x;
  bool active = (i < cb);
  unsigned long long actmask = __ballot(active ? 1 : 0);
  if (actmask == 0ull) return;    // wave-uniform
  int n = 0;
  if (active) n = (k == 0) ? i : (int)list[((k - 1) & 1) * BS * NS + b * NS + i];
  int p = (b << 10) + n;

  float nd0 = 0.f, nd1 = 0.f, nd2 = 0.f, nd3 = 0.f, nd4 = 0.f, nd5 = 0.f;
  if (active) {
    if (k > 0) {
      int t = ts[b];
      regen3(keys[2*(k-1)], keys[2*(k-1)+1], p, sacp[t], s1m[t],
             data, noise_f, noisy_f, nd3, nd4, nd5);
    } else {
      nd3 = noisy_f[p*3+0]; nd4 = noisy_f[p*3+1]; nd5 = noisy_f[p*3+2];
    }
    nd0 = data[p*6+0]; nd1 = data[p*6+1]; nd2 = data[p*6+2];
  }
  float ndsq = nd0*nd0;
  ndsq = fmaf(nd1, nd1, ndsq); ndsq = fmaf(nd2, nd2, ndsq);
  ndsq = fmaf(nd3, nd3, ndsq); ndsq = fmaf(nd4, nd4, ndsq); ndsq = fmaf(nd5, nd5, ndsq);

  const float4* dp = dataP + (size_t)b * 2048;  // wave-uniform base
  float minv = __builtin_inff();
  int mini = 0;
#pragma unroll 4
  for (int m = 0; m < NS; ++m) {
    float4 c0 = dp[2*m];
    float4 c1 = dp[2*m+1];
    float g = nd0 * c0.x;
    g = fmaf(nd1, c0.y, g); g = fmaf(nd2, c0.z, g);
    g = fmaf(nd3, c0.w, g); g = fmaf(nd4, c1.x, g); g = fmaf(nd5, c1.y, g);
    float v = fmaf(-2.0f, g, ndsq + c1.z);  // (|nd|^2 + |d_m|^2) - 2g, 2g exact
    bool lt = v < minv;       // strict < keeps FIRST minimum (jnp.argmin)
    minv = lt ? v : minv;
    mini = lt ? m : mini;
  }
  bool mm = active && (mini != n);
  unsigned long long mask = __ballot(mm ? 1 : 0);
  if (mask != 0ull) {
    int lane = (int)(threadIdx.x & 63);
    int leader = __ffsll((unsigned long long)mask) - 1;
    unsigned basev = 0u;
    if (lane == leader) {
      unsigned cw = (unsigned)__popcll(mask);
      basev = atomicAdd(&cntb[k * BS + b], cw);
      atomicAdd(&cntg[k], cw);
    }
    basev = (unsigned)__shfl((int)basev, leader);
    if (mm) {
      int pos = (int)basev + __popcll(mask & ((1ull << lane) - 1ull));
      list[(k & 1) * BS * NS + b * NS + pos] = (unsigned short)n;
    }
  }
}

// ---- kernel 6: apply the final (iteration 7) update ------------------------
__global__ __launch_bounds__(256) void k_fupd(
    const float* __restrict__ data, const int* __restrict__ ts,
    const float* __restrict__ sacp, const float* __restrict__ s1m,
    const unsigned* __restrict__ keys, const unsigned* __restrict__ cntg,
    const unsigned* __restrict__ cntb, const unsigned short* __restrict__ list,
    float* __restrict__ noise_f, float* __restrict__ noisy_f) {
  for (int j = 0; j < ITERS; ++j) if (cntg[j] < 10u) return;  // cont_7
  int b = blockIdx.x >> 2, chunk = blockIdx.x & 3;
  int cb = (int)cntb[7 * BS + b];
  int i = chunk * 256 + (int)threadIdx.x;
  if (i >= cb) return;
  int n = (int)list[1 * BS * NS + b * NS + i];  // iter 7 parity = 1
  int p = (b << 10) + n;
  int t = ts[b];
  float y3, y4, y5;
  regen3(keys[14], keys[15], p, sacp[t], s1m[t], data, noise_f, noisy_f, y3, y4, y5);
}

// ---- kernel 7: conditional MLP + masked MSE loss per batch -----------------
__global__ __launch_bounds__(256) void k_loss(
    const float* __restrict__ data, const float* __restrict__ noise_f,
    const float* __restrict__ noisy_f, const float* __restrict__ biasb,
    const float4* __restrict__ PA, const float4* __restrict__ PB,
    const float* __restrict__ PC, const float* __restrict__ b2,
    float* __restrict__ out) {
  int b = blockIdx.x, tid = threadIdx.x;
  float x[4][6];
  float acc[4][3];
#pragma unroll
  for (int q = 0; q < 4; ++q) {
    int p = (b << 10) + q * 256 + tid;
    x[q][0] = data[p*6+0]; x[q][1] = data[p*6+1]; x[q][2] = data[p*6+2];
    x[q][3] = noisy_f[p*3+0]; x[q][4] = noisy_f[p*3+1]; x[q][5] = noisy_f[p*3+2];
    acc[q][0] = 0.f; acc[q][1] = 0.f; acc[q][2] = 0.f;
  }
  const float* bb = biasb + (size_t)b * HID;
  for (int j = 0; j < HID; ++j) {
    float4 A = PA[j];
    float4 Bv = PB[j];
    float w25 = PC[j];
    float bj = bb[j];
#pragma unroll
    for (int q = 0; q < 4; ++q) {
      float s = x[q][0] * A.x;
      s = fmaf(x[q][1], A.y, s); s = fmaf(x[q][2], A.z, s);
      s = fmaf(x[q][3], A.w, s); s = fmaf(x[q][4], Bv.x, s);
      s = fmaf(x[q][5], Bv.y, s);
      s += bj;
      float h = tanhf(s);
      acc[q][0] = fmaf(h, Bv.z, acc[q][0]);
      acc[q][1] = fmaf(h, Bv.w, acc[q][1]);
      acc[q][2] = fmaf(h, w25, acc[q][2]);
    }
  }
  float b23 = b2[3], b24 = b2[4], b25 = b2[5];
  float lsum = 0.f;
#pragma unroll
  for (int q = 0; q < 4; ++q) {
    int p = (b << 10) + q * 256 + tid;
    float d0 = (acc[q][0] + b23) - noise_f[p*3+0];
    float d1 = (acc[q][1] + b24) - noise_f[p*3+1];
    float d2 = (acc[q][2] + b25) - noise_f[p*3+2];
    lsum = fmaf(d0, d0, lsum);
    lsum = fmaf(d1, d1, lsum);
    lsum = fmaf(d2, d2, lsum);
  }
  __shared__ float red[256];
  red[tid] = lsum;
  __syncthreads();
  for (int s2 = 128; s2 > 0; s2 >>= 1) {
    if (tid < s2) red[tid] += red[tid + s2];
    __syncthreads();
  }
  if (tid == 0) out[b] = red[0] / 3072.0f;
}

// ---------------------------------------------------------------------------
extern "C" void kernel_launch(void* const* d_in, const int* in_sizes, int n_in,
                              void* d_out, int out_size, void* d_ws, size_t ws_size,
                              hipStream_t stream) {
  (void)in_sizes; (void)n_in; (void)out_size; (void)ws_size;
  const float* data    = (const float*)d_in[0];
  const float* context = (const float*)d_in[1];
  const float* noise0  = (const float*)d_in[2];
  const float* W1      = (const float*)d_in[3];
  const float* Wc      = (const float*)d_in[4];
  const float* Wt      = (const float*)d_in[5];
  const float* b1      = (const float*)d_in[6];
  const float* W2      = (const float*)d_in[7];
  const float* b2      = (const float*)d_in[8];
  const int*   ts      = (const int*)d_in[9];
  float* out = (float*)d_out;

  char* w = (char*)d_ws;
  float*    sacp   = (float*)(w + OFF_SACP);
  float*    s1m    = (float*)(w + OFF_S1M);
  unsigned* keys   = (unsigned*)(w + OFF_KEYS);
  unsigned* cntg   = (unsigned*)(w + OFF_CNTG);
  unsigned* cntb   = (unsigned*)(w + OFF_CNTB);
  unsigned short* list = (unsigned short*)(w + OFF_LIST);
  float4*   dataP  = (float4*)(w + OFF_DATAP);
  float*    noisef = (float*)(w + OFF_NOISE);
  float*    noisyf = (float*)(w + OFF_NOISY);
  float*    biasb  = (float*)(w + OFF_BIAS);
  float4*   PA     = (float4*)(w + OFF_PA);
  float4*   PB     = (float4*)(w + OFF_PB);
  float*    PC     = (float*)(w + OFF_PC);

  k_init<<<1, 256, 0, stream>>>(sacp, s1m, keys, cntg, cntb);
  k_prep<<<512, 256, 0, stream>>>(data, noise0, ts, sacp, s1m, dataP, noisef, noisyf);
  k_bias<<<256, 256, 0, stream>>>(context, Wc, Wt, b1, ts, biasb);
  k_pack<<<2, 256, 0, stream>>>(W1, W2, PA, PB, PC);
  for (int k = 0; k < ITERS; ++k) {
    k_argmin<<<512, 256, 0, stream>>>(k, data, ts, sacp, s1m, keys, cntg, cntb,
                                      list, dataP, noisef, noisyf);
  }
  k_fupd<<<512, 256, 0, stream>>>(data, ts, sacp, s1m, keys, cntg, cntb, list,
                                  noisef, noisyf);
  k_loss<<<128, 256, 0, stream>>>(data, noisef, noisyf, biasb, PA, PB, PC, b2, out);
}

// Round 2
// 697.213 us; speedup vs baseline: 1.7562x; 1.7562x over previous
//
#include <hip/hip_runtime.h>
#include <hip/hip_bf16.h>
#include <math.h>

// ---------------------------------------------------------------------------
// Diffusion renoise-loop + conditional MLP loss, MI355X (gfx950).
// RNG: threefry_partitionable (verified bit-exact round 1, absmax 0.0).
#define BS   128
#define NS   1024
#define HID  512
#define CTX  128
#define TT   100
#define ITERS 8

// ---- workspace layout (bytes) ---------------------------------------------
constexpr size_t OFF_SACP  = 0;        // 100 f32 (pad 512)
constexpr size_t OFF_S1M   = 512;      // 100 f32 (pad 512)
constexpr size_t OFF_KEYS  = 1024;     // 16 u32
constexpr size_t OFF_CNTG  = 1152;     // 8 u32 global mismatch counts
constexpr size_t OFF_CNTB  = 1280;     // 8*128 u32 per-batch counts -> 5376
constexpr size_t OFF_LIST  = 8192;     // u16 [2][128][1024] = 524288 -> 532480
constexpr size_t OFF_DATAP = 532480;   // float4[131072*2] = 4 MiB -> 4726784
constexpr size_t OFF_NOISE = 4726784;  // f32 [128*1024*3] -> 6299648
constexpr size_t OFF_NOISY = 6299648;  // f32 [128*1024*3] -> 7872512
constexpr size_t OFF_BIAS  = 7872512;  // f32 [128*512]    -> 8134656
constexpr size_t OFF_PA    = 8134656;  // float4[512]
constexpr size_t OFF_PB    = 8142848;  // float4[512]
constexpr size_t OFF_PC    = 8151040;  // f32[512] -> 8153088
constexpr size_t OFF_PART  = 8153088;  // f32[512] loss partials -> 8155136

// ---- threefry2x32-20 -------------------------------------------------------
__device__ __forceinline__ unsigned rotl32(unsigned x, int r) {
  return (x << r) | (x >> (32 - r));
}
__device__ __forceinline__ void tf2x32(unsigned k0, unsigned k1,
                                       unsigned x0, unsigned x1,
                                       unsigned& o0, unsigned& o1) {
  unsigned k2 = k0 ^ k1 ^ 0x1BD11BDAu;
  x0 += k0; x1 += k1;
#define TF_R4(a,b,c,d) \
  x0 += x1; x1 = rotl32(x1,(a)); x1 ^= x0; \
  x0 += x1; x1 = rotl32(x1,(b)); x1 ^= x0; \
  x0 += x1; x1 = rotl32(x1,(c)); x1 ^= x0; \
  x0 += x1; x1 = rotl32(x1,(d)); x1 ^= x0;
  TF_R4(13,15,26,6)   x0 += k1; x1 += k2 + 1u;
  TF_R4(17,29,16,24)  x0 += k2; x1 += k0 + 2u;
  TF_R4(13,15,26,6)   x0 += k0; x1 += k1 + 3u;
  TF_R4(17,29,16,24)  x0 += k1; x1 += k2 + 4u;
  TF_R4(13,15,26,6)   x0 += k2; x1 += k0 + 5u;
#undef TF_R4
  o0 = x0; o1 = x1;
}

__device__ __forceinline__ float bits_to_u(unsigned bits) {
  float f = __uint_as_float((bits >> 9) | 0x3f800000u) - 1.0f;
  float u = f * 2.0f + (-0.99999994f);
  return fmaxf(-0.99999994f, u);
}

__device__ __forceinline__ float nrm_from_idx(unsigned k0, unsigned k1, unsigned idx) {
  unsigned o0, o1;
  tf2x32(k0, k1, 0u, idx, o0, o1);
  return 1.41421356f * erfinvf(bits_to_u(o0 ^ o1));
}

// regenerate the 3 free-dim noise values of point p with iteration key (k0,k1)
__device__ __forceinline__ void regen3(unsigned k0, unsigned k1, int p,
                                       float a, float s,
                                       const float* __restrict__ data,
                                       float* __restrict__ noise_f,
                                       float* __restrict__ noisy_f,
                                       float& y3, float& y4, float& y5) {
  unsigned base = (unsigned)p * 6u;
  float z3 = nrm_from_idx(k0, k1, base + 3u);
  float z4 = nrm_from_idx(k0, k1, base + 4u);
  float z5 = nrm_from_idx(k0, k1, base + 5u);
  noise_f[p*3+0] = z3; noise_f[p*3+1] = z4; noise_f[p*3+2] = z5;
  y3 = __fadd_rn(__fmul_rn(a, data[p*6+3]), __fmul_rn(s, z3));
  y4 = __fadd_rn(__fmul_rn(a, data[p*6+4]), __fmul_rn(s, z4));
  y5 = __fadd_rn(__fmul_rn(a, data[p*6+5]), __fmul_rn(s, z5));
  noisy_f[p*3+0] = y3; noisy_f[p*3+1] = y4; noisy_f[p*3+2] = y5;
}

// fast tanh: 1 - 2/(e^{2x}+1); exp/rcp HW units; saturates correctly at +-inf
__device__ __forceinline__ float ftanh(float x) {
  float e = __expf(2.0f * x);
  float r = __builtin_amdgcn_rcpf(e + 1.0f);
  return fmaf(-2.0f, r, 1.0f);
}

// ---- kernel 1: tables, iteration keys, counter init (parallel prefix) ------
__global__ void k_init(float* __restrict__ sacp, float* __restrict__ s1m,
                       unsigned* __restrict__ keys, unsigned* __restrict__ cntg,
                       unsigned* __restrict__ cntb) {
  __shared__ double omb[TT];
  int t = threadIdx.x;
  if (t < TT) {
    const double PI = 3.14159265358979323846;
    double t0 = (double)t / TT, t1 = (double)(t + 1) / TT;
    double c0 = cos((t0 + 0.008) / 1.008 * PI * 0.5); double ab0 = c0 * c0;
    double c1 = cos((t1 + 0.008) / 1.008 * PI * 0.5); double ab1 = c1 * c1;
    double beta = 1.0 - ab1 / ab0;
    if (beta > 0.999) beta = 0.999;
    omb[t] = 1.0 - beta;
  }
  __syncthreads();
  if (t < TT) {
    double acp = 1.0;
    for (int i = 0; i <= t; ++i) acp *= omb[i];
    sacp[t] = (float)sqrt(acp);
    s1m[t]  = (float)sqrt(1.0 - acp);
  }
  if (t >= 128 && t < 128 + ITERS) {
    int k = t - 128;
    unsigned o0, o1;
    tf2x32(0u, 42u, 0u, (unsigned)k, o0, o1);
    keys[2*k] = o0; keys[2*k+1] = o1;
  }
  for (int i = t; i < ITERS; i += blockDim.x) cntg[i] = 0u;
  for (int i = t; i < ITERS * BS; i += blockDim.x) cntb[i] = 0u;
}

// ---- kernel 2: pack data {d0..d5,|d|^2,0}, init noise/noisy (free dims) ----
__global__ __launch_bounds__(256) void k_prep(
    const float* __restrict__ data, const float* __restrict__ noise0,
    const int* __restrict__ ts, const float* __restrict__ sacp,
    const float* __restrict__ s1m,
    float4* __restrict__ dataP, float* __restrict__ noise_f,
    float* __restrict__ noisy_f) {
  int p = blockIdx.x * 256 + threadIdx.x;  // 0..131071
  int b = p >> 10;
  int t = ts[b];
  float a = sacp[t], s = s1m[t];
  const float* dp = data + (size_t)p * 6;
  float d0 = dp[0], d1 = dp[1], d2 = dp[2], d3 = dp[3], d4 = dp[4], d5 = dp[5];
  float dsq = d0*d0;
  dsq = fmaf(d1, d1, dsq); dsq = fmaf(d2, d2, dsq);
  dsq = fmaf(d3, d3, dsq); dsq = fmaf(d4, d4, dsq); dsq = fmaf(d5, d5, dsq);
  dataP[2*p]   = make_float4(d0, d1, d2, d3);
  dataP[2*p+1] = make_float4(d4, d5, dsq, 0.f);
  const float* np0 = noise0 + (size_t)p * 6;
  for (int f = 0; f < 3; ++f) {
    float z = np0[3 + f];
    noise_f[p*3 + f] = z;
    noisy_f[p*3 + f] = __fadd_rn(__fmul_rn(a, dp[3 + f]), __fmul_rn(s, z));
  }
}

// ---- kernel 3: bias = c@Wc + (t/T)*Wt + b1 (blocks 0..255) + weight pack ---
__global__ __launch_bounds__(256) void k_biaspack(
    const float* __restrict__ ctx, const float* __restrict__ Wc,
    const float* __restrict__ Wt, const float* __restrict__ b1,
    const int* __restrict__ ts, float* __restrict__ biasb,
    const float* __restrict__ W1, const float* __restrict__ W2,
    float4* __restrict__ PA, float4* __restrict__ PB, float* __restrict__ PC) {
  if (blockIdx.x == 256) {
    for (int j = threadIdx.x; j < HID; j += 256) {
      PA[j] = make_float4(W1[j], W1[512 + j], W1[1024 + j], W1[1536 + j]);
      PB[j] = make_float4(W1[2048 + j], W1[2560 + j], W2[j*6 + 3], W2[j*6 + 4]);
      PC[j] = W2[j*6 + 5];
    }
    return;
  }
  int idx = blockIdx.x * 256 + threadIdx.x;  // 0..65535
  int b = idx >> 9, j = idx & 511;
  const float* c = ctx + (size_t)b * CTX;
  float acc = 0.f;
  for (int q = 0; q < CTX; ++q) acc = fmaf(c[q], Wc[q * HID + j], acc);
  float temb = (float)ts[b] / 100.0f;
  biasb[idx] = acc + temb * Wt[j] + b1[j];
}

// ---- kernel 4: fused [apply update k-1] + [argmin k, m-split x4] + compact -
// block = 256 threads = 4 waves; wave `seg` scans m in [seg*256,(seg+1)*256)
// for 64 points; cross-seg combine in LDS preserves first-min order.
__global__ __launch_bounds__(256) void k_argmin(
    int k,
    const float* __restrict__ data, const int* __restrict__ ts,
    const float* __restrict__ sacp, const float* __restrict__ s1m,
    const unsigned* __restrict__ keys, unsigned* __restrict__ cntg,
    unsigned* __restrict__ cntb, unsigned short* __restrict__ list,
    const float4* __restrict__ dataP, float* __restrict__ noise_f,
    float* __restrict__ noisy_f) {
  int b = blockIdx.x >> 4, chunk = blockIdx.x & 15;
  if (k > 0) {
    for (int j = 0; j < k; ++j) if (cntg[j] < 10u) return;  // cont chain
  }
  int cb = (k == 0) ? NS : (int)cntb[(k - 1) * BS + b];
  if (chunk * 64 >= cb) return;  // block-uniform
  int pt  = (int)threadIdx.x & 63;
  int seg = __builtin_amdgcn_readfirstlane((int)threadIdx.x >> 6);  // wave-uniform
  int i = chunk * 64 + pt;
  bool active = (i < cb);
  int n = 0;
  if (active) n = (k == 0) ? i : (int)list[((k - 1) & 1) * BS * NS + b * NS + i];
  int p = (b << 10) + n;

  float nd0 = 0.f, nd1 = 0.f, nd2 = 0.f, nd3 = 0.f, nd4 = 0.f, nd5 = 0.f;
  if (active) {
    if (k > 0) {
      int t = ts[b];
      // redundant across 4 segs: identical values, benign
      regen3(keys[2*(k-1)], keys[2*(k-1)+1], p, sacp[t], s1m[t],
             data, noise_f, noisy_f, nd3, nd4, nd5);
    } else {
      nd3 = noisy_f[p*3+0]; nd4 = noisy_f[p*3+1]; nd5 = noisy_f[p*3+2];
    }
    nd0 = data[p*6+0]; nd1 = data[p*6+1]; nd2 = data[p*6+2];
  }
  float ndsq = nd0*nd0;
  ndsq = fmaf(nd1, nd1, ndsq); ndsq = fmaf(nd2, nd2, ndsq);
  ndsq = fmaf(nd3, nd3, ndsq); ndsq = fmaf(nd4, nd4, ndsq); ndsq = fmaf(nd5, nd5, ndsq);

  const float4* dp = dataP + (size_t)b * 2048 + (size_t)seg * 512;  // uniform
  float minv = __builtin_inff();
  int mini = 0;
#pragma unroll 4
  for (int m = 0; m < 256; ++m) {
    float4 c0 = dp[2*m];
    float4 c1 = dp[2*m+1];
    float g = nd0 * c0.x;
    g = fmaf(nd1, c0.y, g); g = fmaf(nd2, c0.z, g);
    g = fmaf(nd3, c0.w, g); g = fmaf(nd4, c1.x, g); g = fmaf(nd5, c1.y, g);
    float v = fmaf(-2.0f, g, ndsq + c1.z);
    bool lt = v < minv;  // strict < keeps FIRST minimum within segment
    minv = lt ? v : minv;
    mini = lt ? m : mini;
  }
  __shared__ float sval[4][64];
  __shared__ int   sidx[4][64];
  sval[seg][pt] = minv;
  sidx[seg][pt] = seg * 256 + mini;
  __syncthreads();
  if (seg == 0) {  // wave 0 combines and does the compaction
    float bv = sval[0][pt];
    int bi = sidx[0][pt];
#pragma unroll
    for (int s2 = 1; s2 < 4; ++s2) {
      float v2 = sval[s2][pt];
      bool lt = v2 < bv;  // strict <: earlier segment wins ties = smaller m
      bv = lt ? v2 : bv;
      bi = lt ? sidx[s2][pt] : bi;
    }
    bool mm = active && (bi != n);
    unsigned long long mask = __ballot(mm ? 1 : 0);
    if (mask != 0ull) {
      int lane = pt;
      int leader = __ffsll((unsigned long long)mask) - 1;
      unsigned basev = 0u;
      if (lane == leader) {
        unsigned cw = (unsigned)__popcll(mask);
        basev = atomicAdd(&cntb[k * BS + b], cw);
        atomicAdd(&cntg[k], cw);
      }
      basev = (unsigned)__shfl((int)basev, leader);
      if (mm) {
        int pos = (int)basev + __popcll(mask & ((1ull << lane) - 1ull));
        list[(k & 1) * BS * NS + b * NS + pos] = (unsigned short)n;
      }
    }
  }
}

// ---- kernel 5: apply the final (iteration 7) update ------------------------
__global__ __launch_bounds__(256) void k_fupd(
    const float* __restrict__ data, const int* __restrict__ ts,
    const float* __restrict__ sacp, const float* __restrict__ s1m,
    const unsigned* __restrict__ keys, const unsigned* __restrict__ cntg,
    const unsigned* __restrict__ cntb, const unsigned short* __restrict__ list,
    float* __restrict__ noise_f, float* __restrict__ noisy_f) {
  for (int j = 0; j < ITERS; ++j) if (cntg[j] < 10u) return;  // cont_7
  int b = blockIdx.x >> 2, chunk = blockIdx.x & 3;
  int cb = (int)cntb[7 * BS + b];
  int i = chunk * 256 + (int)threadIdx.x;
  if (i >= cb) return;
  int n = (int)list[1 * BS * NS + b * NS + i];  // iter 7 parity = 1
  int p = (b << 10) + n;
  int t = ts[b];
  float y3, y4, y5;
  regen3(keys[14], keys[15], p, sacp[t], s1m[t], data, noise_f, noisy_f, y3, y4, y5);
}

// ---- kernel 6: conditional MLP + masked SE partial per quarter-batch -------
// grid 512: block = (b, quarter), 1 point/thread, full j-loop. 2 blocks/CU.
__global__ __launch_bounds__(256) void k_loss(
    const float* __restrict__ data, const float* __restrict__ noise_f,
    const float* __restrict__ noisy_f, const float* __restrict__ biasb,
    const float4* __restrict__ PA, const float4* __restrict__ PB,
    const float* __restrict__ PC, const float* __restrict__ b2,
    float* __restrict__ part) {
  int b = blockIdx.x >> 2, qq = blockIdx.x & 3;
  int tid = threadIdx.x;
  int p = (b << 10) + qq * 256 + tid;
  float x0 = data[p*6+0], x1 = data[p*6+1], x2 = data[p*6+2];
  float x3 = noisy_f[p*3+0], x4 = noisy_f[p*3+1], x5 = noisy_f[p*3+2];
  float a0 = 0.f, a1 = 0.f, a2 = 0.f;
  const float* bb = biasb + (size_t)b * HID;
#pragma unroll 4
  for (int j = 0; j < HID; ++j) {
    float4 A = PA[j];
    float4 Bv = PB[j];
    float s = x0 * A.x;
    s = fmaf(x1, A.y, s); s = fmaf(x2, A.z, s);
    s = fmaf(x3, A.w, s); s = fmaf(x4, Bv.x, s); s = fmaf(x5, Bv.y, s);
    s += bb[j];
    float h = ftanh(s);
    a0 = fmaf(h, Bv.z, a0);
    a1 = fmaf(h, Bv.w, a1);
    a2 = fmaf(h, PC[j], a2);
  }
  float d0 = (a0 + b2[3]) - noise_f[p*3+0];
  float d1 = (a1 + b2[4]) - noise_f[p*3+1];
  float d2 = (a2 + b2[5]) - noise_f[p*3+2];
  float lsum = d0*d0;
  lsum = fmaf(d1, d1, lsum);
  lsum = fmaf(d2, d2, lsum);
  // wave reduce then cross-wave via LDS
#pragma unroll
  for (int off = 32; off > 0; off >>= 1) lsum += __shfl_down(lsum, off);
  __shared__ float red[4];
  if ((tid & 63) == 0) red[tid >> 6] = lsum;
  __syncthreads();
  if (tid == 0) part[blockIdx.x] = red[0] + red[1] + red[2] + red[3];
}

// ---- kernel 7: final reduce: out[b] = sum of 4 partials / 3072 -------------
__global__ void k_red(const float* __restrict__ part, float* __restrict__ out) {
  int b = threadIdx.x;  // 128 threads
  if (b < BS) {
    out[b] = (part[4*b] + part[4*b+1] + part[4*b+2] + part[4*b+3]) / 3072.0f;
  }
}

// ---------------------------------------------------------------------------
extern "C" void kernel_launch(void* const* d_in, const int* in_sizes, int n_in,
                              void* d_out, int out_size, void* d_ws, size_t ws_size,
                              hipStream_t stream) {
  (void)in_sizes; (void)n_in; (void)out_size; (void)ws_size;
  const float* data    = (const float*)d_in[0];
  const float* context = (const float*)d_in[1];
  const float* noise0  = (const float*)d_in[2];
  const float* W1      = (const float*)d_in[3];
  const float* Wc      = (const float*)d_in[4];
  const float* Wt      = (const float*)d_in[5];
  const float* b1      = (const float*)d_in[6];
  const float* W2      = (const float*)d_in[7];
  const float* b2      = (const float*)d_in[8];
  const int*   ts      = (const int*)d_in[9];
  float* out = (float*)d_out;

  char* w = (char*)d_ws;
  float*    sacp   = (float*)(w + OFF_SACP);
  float*    s1m    = (float*)(w + OFF_S1M);
  unsigned* keys   = (unsigned*)(w + OFF_KEYS);
  unsigned* cntg   = (unsigned*)(w + OFF_CNTG);
  unsigned* cntb   = (unsigned*)(w + OFF_CNTB);
  unsigned short* list = (unsigned short*)(w + OFF_LIST);
  float4*   dataP  = (float4*)(w + OFF_DATAP);
  float*    noisef = (float*)(w + OFF_NOISE);
  float*    noisyf = (float*)(w + OFF_NOISY);
  float*    biasb  = (float*)(w + OFF_BIAS);
  float4*   PA     = (float4*)(w + OFF_PA);
  float4*   PB     = (float4*)(w + OFF_PB);
  float*    PC     = (float*)(w + OFF_PC);
  float*    part   = (float*)(w + OFF_PART);

  k_init<<<1, 256, 0, stream>>>(sacp, s1m, keys, cntg, cntb);
  k_biaspack<<<257, 256, 0, stream>>>(context, Wc, Wt, b1, ts, biasb,
                                      W1, W2, PA, PB, PC);
  k_prep<<<512, 256, 0, stream>>>(data, noise0, ts, sacp, s1m, dataP, noisef, noisyf);
  for (int k = 0; k < ITERS; ++k) {
    k_argmin<<<2048, 256, 0, stream>>>(k, data, ts, sacp, s1m, keys, cntg, cntb,
                                       list, dataP, noisef, noisyf);
  }
  k_fupd<<<512, 256, 0, stream>>>(data, ts, sacp, s1m, keys, cntg, cntb, list,
                                  noisef, noisyf);
  k_loss<<<512, 256, 0, stream>>>(data, noisef, noisyf, biasb, PA, PB, PC, b2, part);
  k_red<<<1, 128, 0, stream>>>(part, out);
}

// Round 3
// 647.654 us; speedup vs baseline: 1.8905x; 1.0765x over previous
//
#include <hip/hip_runtime.h>
#include <hip/hip_bf16.h>
#include <hip/hip_fp16.h>
#include <math.h>

// ---------------------------------------------------------------------------
// Diffusion renoise-loop + conditional MLP loss, MI355X (gfx950).
// RNG: threefry_partitionable (bit-exact, absmax 0.0 in rounds 1-2).
// Argmin now via fp16 hi/lo-split MFMA: argmin d2 == argmax (g - dsq/2).
#define BS   128
#define NS   1024
#define HID  512
#define CTX  128
#define TT   100
#define ITERS 8

// ---- workspace layout (bytes) ---------------------------------------------
constexpr size_t OFF_SACP  = 0;         // 100 f32
constexpr size_t OFF_S1M   = 512;       // 100 f32
constexpr size_t OFF_KEYS  = 1024;      // 16 u32
constexpr size_t OFF_CNTG  = 1152;      // 8 u32
constexpr size_t OFF_CNTB  = 1280;      // 8*128 u32 -> 5376
constexpr size_t OFF_LIST  = 8192;      // u16 [2][128][1024] -> 532480
constexpr size_t OFF_BPACK = 532480;    // uint4[128*64*64] = 8 MiB -> 8921088
constexpr size_t OFF_NOISE = 8921088;   // f32 [128*1024*3] -> 10493952
constexpr size_t OFF_NOISY = 10493952;  // f32 [128*1024*3] -> 12066816
constexpr size_t OFF_BIAS  = 12066816;  // f32 [128*512]    -> 12328960
constexpr size_t OFF_PA    = 12328960;  // float4[512]
constexpr size_t OFF_PB    = 12337152;  // float4[512]
constexpr size_t OFF_PC    = 12345344;  // f32[512]
constexpr size_t OFF_PART  = 12347392;  // f32[512] -> 12349440 total ~12.4 MB

typedef __attribute__((ext_vector_type(8))) _Float16 half8;
typedef __attribute__((ext_vector_type(4))) float f32x4;

// ---- threefry2x32-20 -------------------------------------------------------
__device__ __forceinline__ unsigned rotl32(unsigned x, int r) {
  return (x << r) | (x >> (32 - r));
}
__device__ __forceinline__ void tf2x32(unsigned k0, unsigned k1,
                                       unsigned x0, unsigned x1,
                                       unsigned& o0, unsigned& o1) {
  unsigned k2 = k0 ^ k1 ^ 0x1BD11BDAu;
  x0 += k0; x1 += k1;
#define TF_R4(a,b,c,d) \
  x0 += x1; x1 = rotl32(x1,(a)); x1 ^= x0; \
  x0 += x1; x1 = rotl32(x1,(b)); x1 ^= x0; \
  x0 += x1; x1 = rotl32(x1,(c)); x1 ^= x0; \
  x0 += x1; x1 = rotl32(x1,(d)); x1 ^= x0;
  TF_R4(13,15,26,6)   x0 += k1; x1 += k2 + 1u;
  TF_R4(17,29,16,24)  x0 += k2; x1 += k0 + 2u;
  TF_R4(13,15,26,6)   x0 += k0; x1 += k1 + 3u;
  TF_R4(17,29,16,24)  x0 += k1; x1 += k2 + 4u;
  TF_R4(13,15,26,6)   x0 += k2; x1 += k0 + 5u;
#undef TF_R4
  o0 = x0; o1 = x1;
}

__device__ __forceinline__ float bits_to_u(unsigned bits) {
  float f = __uint_as_float((bits >> 9) | 0x3f800000u) - 1.0f;
  float u = f * 2.0f + (-0.99999994f);
  return fmaxf(-0.99999994f, u);
}

__device__ __forceinline__ float nrm_from_idx(unsigned k0, unsigned k1, unsigned idx) {
  unsigned o0, o1;
  tf2x32(k0, k1, 0u, idx, o0, o1);
  return 1.41421356f * erfinvf(bits_to_u(o0 ^ o1));
}

// regenerate the 3 free-dim noise values of point p with iteration key (k0,k1)
__device__ __forceinline__ void regen3(unsigned k0, unsigned k1, int p,
                                       float a, float s,
                                       const float* __restrict__ data,
                                       float* __restrict__ noise_f,
                                       float* __restrict__ noisy_f,
                                       float& y3, float& y4, float& y5) {
  unsigned base = (unsigned)p * 6u;
  float z3 = nrm_from_idx(k0, k1, base + 3u);
  float z4 = nrm_from_idx(k0, k1, base + 4u);
  float z5 = nrm_from_idx(k0, k1, base + 5u);
  noise_f[p*3+0] = z3; noise_f[p*3+1] = z4; noise_f[p*3+2] = z5;
  y3 = __fadd_rn(__fmul_rn(a, data[p*6+3]), __fmul_rn(s, z3));
  y4 = __fadd_rn(__fmul_rn(a, data[p*6+4]), __fmul_rn(s, z4));
  y5 = __fadd_rn(__fmul_rn(a, data[p*6+5]), __fmul_rn(s, z5));
  noisy_f[p*3+0] = y3; noisy_f[p*3+1] = y4; noisy_f[p*3+2] = y5;
}

__device__ __forceinline__ float ftanh(float x) {
  float e = __expf(2.0f * x);
  float r = __builtin_amdgcn_rcpf(e + 1.0f);
  return fmaf(-2.0f, r, 1.0f);
}

// fp16 hi/lo split: x ~= hi + lo with |err| <~ 2^-23 |x|
__device__ __forceinline__ void split16(float x, unsigned short& hi, unsigned short& lo) {
  __half h = __float2half(x);
  float hf = __half2float(h);
  __half l = __float2half(x - hf);
  hi = __half_as_ushort(h);
  lo = __half_as_ushort(l);
}
__device__ __forceinline__ unsigned pack2(unsigned short a, unsigned short b) {
  return (unsigned)a | ((unsigned)b << 16);
}

// ---- kernel 1: tables, iteration keys, counter init ------------------------
__global__ void k_init(float* __restrict__ sacp, float* __restrict__ s1m,
                       unsigned* __restrict__ keys, unsigned* __restrict__ cntg,
                       unsigned* __restrict__ cntb) {
  __shared__ double omb[TT];
  int t = threadIdx.x;
  if (t < TT) {
    const double PI = 3.14159265358979323846;
    double t0 = (double)t / TT, t1 = (double)(t + 1) / TT;
    double c0 = cos((t0 + 0.008) / 1.008 * PI * 0.5); double ab0 = c0 * c0;
    double c1 = cos((t1 + 0.008) / 1.008 * PI * 0.5); double ab1 = c1 * c1;
    double beta = 1.0 - ab1 / ab0;
    if (beta > 0.999) beta = 0.999;
    omb[t] = 1.0 - beta;
  }
  __syncthreads();
  if (t < TT) {
    double acp = 1.0;
    for (int i = 0; i <= t; ++i) acp *= omb[i];
    sacp[t] = (float)sqrt(acp);
    s1m[t]  = (float)sqrt(1.0 - acp);
  }
  if (t >= 128 && t < 128 + ITERS) {
    int k = t - 128;
    unsigned o0, o1;
    tf2x32(0u, 42u, 0u, (unsigned)k, o0, o1);
    keys[2*k] = o0; keys[2*k+1] = o1;
  }
  for (int i = t; i < ITERS; i += blockDim.x) cntg[i] = 0u;
  for (int i = t; i < ITERS * BS; i += blockDim.x) cntb[i] = 0u;
}

// ---- kernel 2: init noise/noisy (free dims) + build Bpack fragments --------
// B-row K-encoding (per candidate c): word w=2d & 2d+1 = pack(hi_d, lo_d)
// for d=0..5; word 12 = pack of split(-dsq/2); words 13..15 = 0.
__global__ __launch_bounds__(256) void k_prep(
    const float* __restrict__ data, const float* __restrict__ noise0,
    const int* __restrict__ ts, const float* __restrict__ sacp,
    const float* __restrict__ s1m,
    uint4* __restrict__ Bpack, float* __restrict__ noise_f,
    float* __restrict__ noisy_f) {
  int p = blockIdx.x * 256 + threadIdx.x;  // 0..131071
  int b = p >> 10, c = p & 1023;
  int t = ts[b];
  float a = sacp[t], s = s1m[t];
  const float* dp = data + (size_t)p * 6;
  float d0 = dp[0], d1 = dp[1], d2 = dp[2], d3 = dp[3], d4 = dp[4], d5 = dp[5];
  float dsq = d0*d0;
  dsq = fmaf(d1, d1, dsq); dsq = fmaf(d2, d2, dsq);
  dsq = fmaf(d3, d3, dsq); dsq = fmaf(d4, d4, dsq); dsq = fmaf(d5, d5, dsq);
  const float* np0 = noise0 + (size_t)p * 6;
  for (int f = 0; f < 3; ++f) {
    float z = np0[3 + f];
    noise_f[p*3 + f] = z;
    noisy_f[p*3 + f] = __fadd_rn(__fmul_rn(a, dp[3 + f]), __fmul_rn(s, z));
  }
  unsigned wds[13];
  float dd[6] = {d0, d1, d2, d3, d4, d5};
#pragma unroll
  for (int d = 0; d < 6; ++d) {
    unsigned short hi, lo; split16(dd[d], hi, lo);
    unsigned pk = pack2(hi, lo);
    wds[2*d] = pk; wds[2*d+1] = pk;
  }
  {
    unsigned short hi, lo; split16(-0.5f * dsq, hi, lo);
    wds[12] = pack2(hi, lo);
  }
  int ct = c >> 4, c15 = c & 15;
  uint4* dst = Bpack + ((size_t)(b * 64 + ct)) * 64;
#pragma unroll
  for (int q = 0; q < 4; ++q) {
    uint4 v;
    v.x = (q*4+0 < 13) ? wds[q*4+0] : 0u;
    v.y = (q*4+1 < 13) ? wds[q*4+1] : 0u;
    v.z = (q*4+2 < 13) ? wds[q*4+2] : 0u;
    v.w = (q*4+3 < 13) ? wds[q*4+3] : 0u;
    dst[q * 16 + c15] = v;
  }
}

// ---- kernel 3: bias = c@Wc + (t/T)*Wt + b1 (blocks 0..255) + weight pack ---
__global__ __launch_bounds__(256) void k_biaspack(
    const float* __restrict__ ctx, const float* __restrict__ Wc,
    const float* __restrict__ Wt, const float* __restrict__ b1,
    const int* __restrict__ ts, float* __restrict__ biasb,
    const float* __restrict__ W1, const float* __restrict__ W2,
    float4* __restrict__ PA, float4* __restrict__ PB, float* __restrict__ PC) {
  if (blockIdx.x == 256) {
    for (int j = threadIdx.x; j < HID; j += 256) {
      PA[j] = make_float4(W1[j], W1[512 + j], W1[1024 + j], W1[1536 + j]);
      PB[j] = make_float4(W1[2048 + j], W1[2560 + j], W2[j*6 + 3], W2[j*6 + 4]);
      PC[j] = W2[j*6 + 5];
    }
    return;
  }
  int idx = blockIdx.x * 256 + threadIdx.x;
  int b = idx >> 9, j = idx & 511;
  const float* c = ctx + (size_t)b * CTX;
  float acc = 0.f;
  for (int q = 0; q < CTX; ++q) acc = fmaf(c[q], Wc[q * HID + j], acc);
  float temb = (float)ts[b] / 100.0f;
  biasb[idx] = acc + temb * Wt[j] + b1[j];
}

// ---- kernel 4: MFMA argmin sweep -------------------------------------------
// blockIdx = qb*128 + b (XCD swizzle: all 8 blocks of batch b share one XCD).
// Block: 4 waves; wave handles 32 queries = 2 M-tiles of 16; c-loop over 64
// candidate tiles; per tile one mfma_f32_16x16x32_f16 per M-tile.
// C/D layout: col(c) = lane&15, row(q) = (lane>>4)*4 + reg  [m89-verified].
// A layout: m = lane&15, k = (lane>>4)*8 + j.
__global__ __launch_bounds__(256) void k_argmin(
    int k,
    const float* __restrict__ data, const int* __restrict__ ts,
    const float* __restrict__ sacp, const float* __restrict__ s1m,
    const unsigned* __restrict__ keys, unsigned* __restrict__ cntg,
    unsigned* __restrict__ cntb, unsigned short* __restrict__ list,
    const uint4* __restrict__ Bpack, float* __restrict__ noise_f,
    float* __restrict__ noisy_f) {
  int b = blockIdx.x & 127, qb = blockIdx.x >> 7;
  if (k > 0) {
    for (int j = 0; j < k; ++j) if (cntg[j] < 10u) return;  // cont chain
  }
  int cb = (k == 0) ? NS : (int)cntb[(k - 1) * BS + b];
  if (qb * 128 >= cb) return;  // block-uniform
  int tid = (int)threadIdx.x;
  int w = tid >> 6, lane = tid & 63;
  int c15 = lane & 15, quad = lane >> 4;
  __shared__ unsigned rowbuf[4][32][20];  // stride 20 u32: 16B-aligned, 2-way banks
  __shared__ int snn[4][32];
  int i0w = qb * 128 + w * 32;

  // ---- build phase: lanes 0..31 each build one query row (A K-encoding) ---
  if (lane < 32) {
    int i = i0w + lane;
    bool act = (i < cb);
    int n = 0;
    if (act) n = (k == 0) ? i : (int)list[((k - 1) & 1) * BS * NS + b * NS + i];
    snn[w][lane] = n;
    float nd[6] = {0.f, 0.f, 0.f, 0.f, 0.f, 0.f};
    if (act) {
      int p = (b << 10) + n;
      nd[0] = data[p*6+0]; nd[1] = data[p*6+1]; nd[2] = data[p*6+2];
      if (k > 0) {
        int t = ts[b];
        regen3(keys[2*(k-1)], keys[2*(k-1)+1], p, sacp[t], s1m[t],
               data, noise_f, noisy_f, nd[3], nd[4], nd[5]);
      } else {
        nd[3] = noisy_f[p*3+0]; nd[4] = noisy_f[p*3+1]; nd[5] = noisy_f[p*3+2];
      }
    }
    unsigned* r = rowbuf[w][lane];
#pragma unroll
    for (int d = 0; d < 6; ++d) {
      unsigned short hi, lo; split16(nd[d], hi, lo);
      r[2*d]   = pack2(hi, hi);
      r[2*d+1] = pack2(lo, lo);
    }
    unsigned short oneh = act ? (unsigned short)0x3C00 : (unsigned short)0;
    r[12] = pack2(oneh, oneh);
    r[13] = 0u; r[14] = 0u; r[15] = 0u;
  }
  __syncthreads();
  if (i0w >= cb) return;  // whole wave inactive (no later barriers)

  half8 af0 = __builtin_bit_cast(half8, *(const uint4*)&rowbuf[w][c15][quad*4]);
  half8 af1 = __builtin_bit_cast(half8, *(const uint4*)&rowbuf[w][16 + c15][quad*4]);

  const uint4* bp = Bpack + (size_t)b * 64 * 64 + lane;
  float bv0[4], bv1[4];
  int   bt0[4], bt1[4];
#pragma unroll
  for (int r = 0; r < 4; ++r) {
    bv0[r] = -__builtin_inff(); bv1[r] = -__builtin_inff();
    bt0[r] = 0; bt1[r] = 0;
  }
#pragma unroll 2
  for (int ct = 0; ct < 64; ++ct) {
    half8 bf = __builtin_bit_cast(half8, bp[ct * 64]);
    f32x4 z = {0.f, 0.f, 0.f, 0.f};
    f32x4 a0 = __builtin_amdgcn_mfma_f32_16x16x32_f16(af0, bf, z, 0, 0, 0);
    f32x4 a1 = __builtin_amdgcn_mfma_f32_16x16x32_f16(af1, bf, z, 0, 0, 0);
#pragma unroll
    for (int r = 0; r < 4; ++r) {
      if (a0[r] > bv0[r]) { bv0[r] = a0[r]; bt0[r] = ct; }  // strict >: first min
      if (a1[r] > bv1[r]) { bv1[r] = a1[r]; bt1[r] = ct; }
    }
  }
  int bc0[4], bc1[4];
#pragma unroll
  for (int r = 0; r < 4; ++r) {
    bc0[r] = bt0[r] * 16 + c15;
    bc1[r] = bt1[r] * 16 + c15;
  }
  // butterfly argmax over the 16 cols (ties -> smaller candidate index)
#pragma unroll
  for (int m = 1; m < 16; m <<= 1) {
#pragma unroll
    for (int r = 0; r < 4; ++r) {
      float ov = __shfl_xor(bv0[r], m);
      int   oc = __shfl_xor(bc0[r], m);
      bool tk = (ov > bv0[r]) || (ov == bv0[r] && oc < bc0[r]);
      if (tk) { bv0[r] = ov; bc0[r] = oc; }
      ov = __shfl_xor(bv1[r], m);
      oc = __shfl_xor(bc1[r], m);
      tk = (ov > bv1[r]) || (ov == bv1[r] && oc < bc1[r]);
      if (tk) { bv1[r] = ov; bc1[r] = oc; }
    }
  }
  // writers: lane with c15 = reg r emits row (quad*4 + r) of each tile
  int r = c15;
  int sel0 = (r == 0) ? bc0[0] : (r == 1) ? bc0[1] : (r == 2) ? bc0[2] : bc0[3];
  int sel1 = (r == 0) ? bc1[0] : (r == 1) ? bc1[1] : (r == 2) ? bc1[2] : bc1[3];
#pragma unroll
  for (int t2 = 0; t2 < 2; ++t2) {
    bool mm = false; int n = 0;
    if (r < 4) {
      int ql = t2 * 16 + quad * 4 + r;
      int i = i0w + ql;
      n = snn[w][ql];
      int bestc = t2 ? sel1 : sel0;
      mm = (i < cb) && (bestc != n);
    }
    unsigned long long mask = __ballot(mm ? 1 : 0);
    if (mask != 0ull) {
      int leader = __ffsll((unsigned long long)mask) - 1;
      unsigned basev = 0u;
      if (lane == leader) {
        unsigned cw = (unsigned)__popcll(mask);
        basev = atomicAdd(&cntb[k * BS + b], cw);
        atomicAdd(&cntg[k], cw);
      }
      basev = (unsigned)__shfl((int)basev, leader);
      if (mm) {
        int pos = (int)basev + __popcll(mask & ((1ull << lane) - 1ull));
        list[(k & 1) * BS * NS + b * NS + pos] = (unsigned short)n;
      }
    }
  }
}

// ---- kernel 5: apply the final (iteration 7) update ------------------------
__global__ __launch_bounds__(256) void k_fupd(
    const float* __restrict__ data, const int* __restrict__ ts,
    const float* __restrict__ sacp, const float* __restrict__ s1m,
    const unsigned* __restrict__ keys, const unsigned* __restrict__ cntg,
    const unsigned* __restrict__ cntb, const unsigned short* __restrict__ list,
    float* __restrict__ noise_f, float* __restrict__ noisy_f) {
  for (int j = 0; j < ITERS; ++j) if (cntg[j] < 10u) return;  // cont_7
  int b = blockIdx.x >> 2, chunk = blockIdx.x & 3;
  int cb = (int)cntb[7 * BS + b];
  int i = chunk * 256 + (int)threadIdx.x;
  if (i >= cb) return;
  int n = (int)list[1 * BS * NS + b * NS + i];  // iter 7 parity = 1
  int p = (b << 10) + n;
  int t = ts[b];
  float y3, y4, y5;
  regen3(keys[14], keys[15], p, sacp[t], s1m[t], data, noise_f, noisy_f, y3, y4, y5);
}

// ---- kernel 6: conditional MLP + masked SE partial per quarter-batch -------
__global__ __launch_bounds__(256) void k_loss(
    const float* __restrict__ data, const float* __restrict__ noise_f,
    const float* __restrict__ noisy_f, const float* __restrict__ biasb,
    const float4* __restrict__ PA, const float4* __restrict__ PB,
    const float* __restrict__ PC, const float* __restrict__ b2,
    float* __restrict__ part) {
  int b = blockIdx.x >> 2, qq = blockIdx.x & 3;
  int tid = threadIdx.x;
  int p = (b << 10) + qq * 256 + tid;
  float x0 = data[p*6+0], x1 = data[p*6+1], x2 = data[p*6+2];
  float x3 = noisy_f[p*3+0], x4 = noisy_f[p*3+1], x5 = noisy_f[p*3+2];
  float a0 = 0.f, a1 = 0.f, a2 = 0.f;
  const float* bb = biasb + (size_t)b * HID;
#pragma unroll 4
  for (int j = 0; j < HID; ++j) {
    float4 A = PA[j];
    float4 Bv = PB[j];
    float s = x0 * A.x;
    s = fmaf(x1, A.y, s); s = fmaf(x2, A.z, s);
    s = fmaf(x3, A.w, s); s = fmaf(x4, Bv.x, s); s = fmaf(x5, Bv.y, s);
    s += bb[j];
    float h = ftanh(s);
    a0 = fmaf(h, Bv.z, a0);
    a1 = fmaf(h, Bv.w, a1);
    a2 = fmaf(h, PC[j], a2);
  }
  float d0 = (a0 + b2[3]) - noise_f[p*3+0];
  float d1 = (a1 + b2[4]) - noise_f[p*3+1];
  float d2 = (a2 + b2[5]) - noise_f[p*3+2];
  float lsum = d0*d0;
  lsum = fmaf(d1, d1, lsum);
  lsum = fmaf(d2, d2, lsum);
#pragma unroll
  for (int off = 32; off > 0; off >>= 1) lsum += __shfl_down(lsum, off);
  __shared__ float red[4];
  if ((tid & 63) == 0) red[tid >> 6] = lsum;
  __syncthreads();
  if (tid == 0) part[blockIdx.x] = red[0] + red[1] + red[2] + red[3];
}

// ---- kernel 7: final reduce ------------------------------------------------
__global__ void k_red(const float* __restrict__ part, float* __restrict__ out) {
  int b = threadIdx.x;
  if (b < BS) {
    out[b] = (part[4*b] + part[4*b+1] + part[4*b+2] + part[4*b+3]) / 3072.0f;
  }
}

// ---------------------------------------------------------------------------
extern "C" void kernel_launch(void* const* d_in, const int* in_sizes, int n_in,
                              void* d_out, int out_size, void* d_ws, size_t ws_size,
                              hipStream_t stream) {
  (void)in_sizes; (void)n_in; (void)out_size; (void)ws_size;
  const float* data    = (const float*)d_in[0];
  const float* context = (const float*)d_in[1];
  const float* noise0  = (const float*)d_in[2];
  const float* W1      = (const float*)d_in[3];
  const float* Wc      = (const float*)d_in[4];
  const float* Wt      = (const float*)d_in[5];
  const float* b1      = (const float*)d_in[6];
  const float* W2      = (const float*)d_in[7];
  const float* b2      = (const float*)d_in[8];
  const int*   ts      = (const int*)d_in[9];
  float* out = (float*)d_out;

  char* w = (char*)d_ws;
  float*    sacp   = (float*)(w + OFF_SACP);
  float*    s1m    = (float*)(w + OFF_S1M);
  unsigned* keys   = (unsigned*)(w + OFF_KEYS);
  unsigned* cntg   = (unsigned*)(w + OFF_CNTG);
  unsigned* cntb   = (unsigned*)(w + OFF_CNTB);
  unsigned short* list = (unsigned short*)(w + OFF_LIST);
  uint4*    Bpack  = (uint4*)(w + OFF_BPACK);
  float*    noisef = (float*)(w + OFF_NOISE);
  float*    noisyf = (float*)(w + OFF_NOISY);
  float*    biasb  = (float*)(w + OFF_BIAS);
  float4*   PA     = (float4*)(w + OFF_PA);
  float4*   PB     = (float4*)(w + OFF_PB);
  float*    PC     = (float*)(w + OFF_PC);
  float*    part   = (float*)(w + OFF_PART);

  k_init<<<1, 256, 0, stream>>>(sacp, s1m, keys, cntg, cntb);
  k_biaspack<<<257, 256, 0, stream>>>(context, Wc, Wt, b1, ts, biasb,
                                      W1, W2, PA, PB, PC);
  k_prep<<<512, 256, 0, stream>>>(data, noise0, ts, sacp, s1m, Bpack, noisef, noisyf);
  for (int k = 0; k < ITERS; ++k) {
    k_argmin<<<1024, 256, 0, stream>>>(k, data, ts, sacp, s1m, keys, cntg, cntb,
                                       list, Bpack, noisef, noisyf);
  }
  k_fupd<<<512, 256, 0, stream>>>(data, ts, sacp, s1m, keys, cntg, cntb, list,
                                  noisef, noisyf);
  k_loss<<<512, 256, 0, stream>>>(data, noisef, noisyf, biasb, PA, PB, PC, b2, part);
  k_red<<<1, 128, 0, stream>>>(part, out);
}